// Round 1
// 270.585 us; speedup vs baseline: 1.1205x; 1.1205x over previous
//
#include <hip/hip_runtime.h>
#include <stdint.h>
#include <stddef.h>

// GraphSAGE-mean 2-layer pipeline on MI355X — round 5.
//   h   = relu(feat @ W_init + b_init)                      [200000,128] bf16 (ws)
//   l0: hn = segment_mean(h[src0], dst0); h1 = relu(h[:50000]@Ws + hn@Wn + b)  bf16
//   l1: hn = segment_mean(h1[src1], dst1); out = h1[:10000]@Ws + hn@Wn + b    f32
//
// R5 changes vs R4:
//  - place + fc_init fused into one kernel (even blocks = place, odd = fc):
//    the two are data-independent; fusing turns sum into max. Interleaved
//    roles so both are co-resident from dispatch 0.
//  - fc_init: W fragments now live in VGPRs (64 regs/wave, per-wave nt-half
//    only) instead of 32 KB LDS -> LDS = 32 KB tiles only -> 4 blocks/CU
//    (was 2). Tile reads XOR-swizzled (granule ^= row&7) with pre-swizzled
//    global source for global_load_lds (both-sides-or-neither) -> even
//    8-lane/bank-quad spread on ds_read_b128.
//  - agg: gather widened 4B->16B per lane (4 rows / 1 KB per instruction,
//    2-deep unroll = 8 edges in flight), cross-quarter shfl_xor reduction.

#define DIM 128
constexpr int N_SRC0 = 200000;
constexpr int N_DST0 = 50000;
constexpr int N_DST1 = 10000;
constexpr int E0 = 800000;
constexpr int E1 = 160000;
constexpr int MAXDEG = 64;   // Poisson(16): P(deg>64) ~ e^-42 * 50k — impossible

constexpr int FC_BLOCKS = 1024;     // odd blocks of the fused kernel
constexpr int PLACE_BLOCKS = 1024;  // even blocks of the fused kernel

typedef __attribute__((ext_vector_type(8))) short bf16x8;   // 8 bf16 = 4 VGPRs
typedef __attribute__((ext_vector_type(4))) float f32x4;    // MFMA C/D

__device__ __forceinline__ uint16_t f2bf(float f) {
  union { float f; uint32_t u; } v; v.f = f;
  return (uint16_t)((v.u + 0x7FFFu + ((v.u >> 16) & 1u)) >> 16);  // RNE
}
__device__ __forceinline__ float bf2f(uint16_t h) {
  union { uint32_t u; float f; } v; v.u = ((uint32_t)h) << 16;
  return v.f;
}

// ---------------------------------------------------------------------------
// prep: reformat 3 weight matrices (f32) into MFMA-fragment-order bf16 planes,
// and zero the degree counters.
// Wf[m][((kc*8+nt)*64+lane)*8+j] = bf16(W_m[kc*32+(lane>>4)*8+j][nt*16+(lane&15)])
// ---------------------------------------------------------------------------
__global__ __launch_bounds__(512) void prep_w_kernel(
    const float* __restrict__ W0, const float* __restrict__ W1,
    const float* __restrict__ W2, uint16_t* __restrict__ Wf,
    int* __restrict__ cnt, int ncnt) {
  int gid = blockIdx.x * 512 + threadIdx.x;
  if (gid < 3 * 16384) {
    int m = gid >> 14, idx = gid & 16383;
    const float* W = m == 0 ? W0 : (m == 1 ? W1 : W2);
    int j = idx & 7, lane = (idx >> 3) & 63, nt = (idx >> 9) & 7, kc = idx >> 12;
    int k = kc * 32 + (lane >> 4) * 8 + j;
    int n = nt * 16 + (lane & 15);
    Wf[gid] = f2bf(W[k * DIM + n]);
  }
  int z = gid - 3 * 16384;
  if (z >= 0 && z < ncnt) cnt[z] = 0;
}

// ---------------------------------------------------------------------------
// fused place + fc_init.
//   even blocks: dst-partitioned edge slot-scatter (partition=(bid>>1)&7;
//     partitions p and p+4 share an XCD -> 3.3 MB of cnt+eslot slice per L2,
//     still resident).
//   odd blocks: h = relu(feat @ W + b). 32-row feat tiles double-buffered via
//     global_load_lds (XOR-swizzled granules), W frags in VGPRs, 32 KB LDS.
// ---------------------------------------------------------------------------
__global__ __launch_bounds__(256, 4) void place_fc_kernel(
    const int* __restrict__ src0, const int* __restrict__ dst0,
    const int* __restrict__ src1, const int* __restrict__ dst1,
    int* __restrict__ cnt0, int* __restrict__ cnt1,
    int* __restrict__ eslot0, int* __restrict__ eslot1,
    const float* __restrict__ feat, const uint16_t* __restrict__ Wf,
    const float* __restrict__ bias, uint16_t* __restrict__ hout) {
  __shared__ __align__(16) float tile[2][4096];   // 2 x 32 rows x 128 cols f32

  if ((blockIdx.x & 1) == 0) {
    // ---------------- place role ----------------
    int pb = blockIdx.x >> 1;        // 0..PLACE_BLOCKS-1
    int part = pb & 7;
    int bpp  = PLACE_BLOCKS >> 3;    // blocks per partition
    int bidx = pb >> 3;
    const int4* s04 = (const int4*)src0;
    const int4* d04 = (const int4*)dst0;
    const int4* s14 = (const int4*)src1;
    const int4* d14 = (const int4*)dst1;

    // layer 0: dst slice [part*6250, part*6250+6250)
    int lo = part * (N_DST0 / 8), hi = lo + (N_DST0 / 8);
    for (int i = bidx * 256 + threadIdx.x; i < E0 / 4; i += bpp * 256) {
      int4 d = d04[i]; int4 s = s04[i];
      if (d.x >= lo && d.x < hi) { int p = atomicAdd(&cnt0[d.x], 1); if (p < MAXDEG) eslot0[(size_t)d.x * MAXDEG + p] = s.x; }
      if (d.y >= lo && d.y < hi) { int p = atomicAdd(&cnt0[d.y], 1); if (p < MAXDEG) eslot0[(size_t)d.y * MAXDEG + p] = s.y; }
      if (d.z >= lo && d.z < hi) { int p = atomicAdd(&cnt0[d.z], 1); if (p < MAXDEG) eslot0[(size_t)d.z * MAXDEG + p] = s.z; }
      if (d.w >= lo && d.w < hi) { int p = atomicAdd(&cnt0[d.w], 1); if (p < MAXDEG) eslot0[(size_t)d.w * MAXDEG + p] = s.w; }
    }
    // layer 1: dst slice [part*1250, part*1250+1250)
    int lo1 = part * (N_DST1 / 8), hi1 = lo1 + (N_DST1 / 8);
    for (int i = bidx * 256 + threadIdx.x; i < E1 / 4; i += bpp * 256) {
      int4 d = d14[i]; int4 s = s14[i];
      if (d.x >= lo1 && d.x < hi1) { int p = atomicAdd(&cnt1[d.x], 1); if (p < MAXDEG) eslot1[(size_t)d.x * MAXDEG + p] = s.x; }
      if (d.y >= lo1 && d.y < hi1) { int p = atomicAdd(&cnt1[d.y], 1); if (p < MAXDEG) eslot1[(size_t)d.y * MAXDEG + p] = s.y; }
      if (d.z >= lo1 && d.z < hi1) { int p = atomicAdd(&cnt1[d.z], 1); if (p < MAXDEG) eslot1[(size_t)d.z * MAXDEG + p] = s.z; }
      if (d.w >= lo1 && d.w < hi1) { int p = atomicAdd(&cnt1[d.w], 1); if (p < MAXDEG) eslot1[(size_t)d.w * MAXDEG + p] = s.w; }
    }
    return;
  }

  // ---------------- fc role ----------------
  const int tid = threadIdx.x;
  const int w = tid >> 6, lane = tid & 63;
  const int q = lane >> 4, m16 = lane & 15;
  const int sl = w >> 1, nh = w & 1;   // strip-in-tile, nt-half

  // W fragments for this wave's nt-half: 4 kc x 4 j x bf16x8 = 64 VGPRs
  bf16x8 wv[4][4];
#pragma unroll
  for (int kc = 0; kc < 4; kc++)
#pragma unroll
    for (int j = 0; j < 4; j++)
      wv[kc][j] = *(const bf16x8*)&Wf[((size_t)((kc * 8 + nh * 4 + j) * 64 + lane)) * 8];

  float bv[4];
#pragma unroll
  for (int j = 0; j < 4; j++) bv[j] = bias[(nh * 4 + j) * 16 + m16];

  const int ntiles = N_SRC0 / 32;   // 6250

  // stage tile t into tile[buf]: LDS dest is linear (wave-uniform base +
  // lane*16); global source pre-swizzled so LDS granule G of row r holds
  // global granule G ^ (r&7).  4 issues/wave x 1 KB.
  const int lrow0 = w * 8 + (lane >> 5);
  auto stage = [&](int t, int buf) {
#pragma unroll
    for (int i = 0; i < 4; i++) {
      int row = lrow0 + i * 2;
      int g = (lane & 31) ^ (row & 7);
      const float* gs = feat + (size_t)t * 4096 + row * 128 + g * 4;
      float* ld = &tile[buf][w * 1024 + i * 256];
      __builtin_amdgcn_global_load_lds(
          (const __attribute__((address_space(1))) uint32_t*)gs,
          (__attribute__((address_space(3))) uint32_t*)ld,
          16, 0, 0);
    }
  };

  int t = blockIdx.x >> 1;   // 0..FC_BLOCKS-1
  int cur = 0;
  if (t < ntiles) stage(t, 0);
  __syncthreads();

  const int trow = sl * 16 + m16;
  const int sw = trow & 7;

  while (t < ntiles) {
    int tn = t + FC_BLOCKS;
    if (tn < ntiles) stage(tn, cur ^ 1);   // async prefetch into other buffer

    f32x4 acc[4];
#pragma unroll
    for (int j = 0; j < 4; j++) acc[j] = (f32x4){0.f, 0.f, 0.f, 0.f};

    const char* rb = (const char*)&tile[cur][0] + trow * 512;
#pragma unroll
    for (int kc = 0; kc < 4; kc++) {
      int g0 = kc * 8 + q * 2;
      float4 x0 = *(const float4*)(rb + ((g0    ) ^ sw) * 16);
      float4 x1 = *(const float4*)(rb + ((g0 + 1) ^ sw) * 16);
      bf16x8 a;
      a[0] = (short)f2bf(x0.x); a[1] = (short)f2bf(x0.y);
      a[2] = (short)f2bf(x0.z); a[3] = (short)f2bf(x0.w);
      a[4] = (short)f2bf(x1.x); a[5] = (short)f2bf(x1.y);
      a[6] = (short)f2bf(x1.z); a[7] = (short)f2bf(x1.w);
#pragma unroll
      for (int j = 0; j < 4; j++)
        acc[j] = __builtin_amdgcn_mfma_f32_16x16x32_bf16(a, wv[kc][j], acc[j], 0, 0, 0);
    }

    int rowb = t * 32 + sl * 16 + q * 4;
#pragma unroll
    for (int j = 0; j < 4; j++)
#pragma unroll
      for (int r = 0; r < 4; r++) {
        float v = fmaxf(acc[j][r] + bv[j], 0.f);
        hout[(size_t)(rowb + r) * DIM + (nh * 4 + j) * 16 + m16] = f2bf(v);
      }

    __syncthreads();   // tile[cur] consumed; staged tile ready (vmcnt drain)
    cur ^= 1;
    t = tn;
  }
}

// ---------------------------------------------------------------------------
// aggregate: wave per dst. Lane = (quarter qr, col-group c): loads 16 B
// (8 bf16 cols) of edge e+qr -> 4 rows / 1 KB per instruction. 2-deep unroll
// = 8 edges in flight. Cross-quarter shfl_xor(16/32) reduce; qr==0 writes.
// ---------------------------------------------------------------------------
__global__ __launch_bounds__(256) void agg_kernel(
    const int* __restrict__ eslot, const int* __restrict__ deg,
    const uint16_t* __restrict__ hsrc, uint16_t* __restrict__ hout, int n_dst) {
  int d = (blockIdx.x * 256 + threadIdx.x) >> 6;
  int lane = threadIdx.x & 63;
  if (d >= n_dst) return;
  const int* sl = eslot + (size_t)d * MAXDEG;
  int dg = deg[d];
  int dgc = dg < MAXDEG ? dg : MAXDEG;
  int qr = lane >> 4;        // which edge within a group of 4
  int c  = lane & 15;        // owns cols c*8 .. c*8+7

  float a0 = 0.f, a1 = 0.f, a2 = 0.f, a3 = 0.f;
  float a4 = 0.f, a5 = 0.f, a6 = 0.f, a7 = 0.f;

#define ACC4(P)                                                          \
  a0 += bf2f((uint16_t)(P).x); a1 += bf2f((uint16_t)((P).x >> 16));      \
  a2 += bf2f((uint16_t)(P).y); a3 += bf2f((uint16_t)((P).y >> 16));      \
  a4 += bf2f((uint16_t)(P).z); a5 += bf2f((uint16_t)((P).z >> 16));      \
  a6 += bf2f((uint16_t)(P).w); a7 += bf2f((uint16_t)((P).w >> 16));

  int e = 0;
  for (; e + 8 <= dgc; e += 8) {
    int s0 = sl[e + qr];
    int s1 = sl[e + 4 + qr];
    uint4 p0 = *(const uint4*)(hsrc + (size_t)s0 * DIM + c * 8);
    uint4 p1 = *(const uint4*)(hsrc + (size_t)s1 * DIM + c * 8);
    ACC4(p0); ACC4(p1);
  }
  for (; e + 4 <= dgc; e += 4) {
    int s0 = sl[e + qr];
    uint4 p0 = *(const uint4*)(hsrc + (size_t)s0 * DIM + c * 8);
    ACC4(p0);
  }
  int rem = dgc - e;
  if (qr < rem) {
    int s0 = sl[e + qr];
    uint4 p0 = *(const uint4*)(hsrc + (size_t)s0 * DIM + c * 8);
    ACC4(p0);
  }
#undef ACC4

  a0 += __shfl_xor(a0, 16); a0 += __shfl_xor(a0, 32);
  a1 += __shfl_xor(a1, 16); a1 += __shfl_xor(a1, 32);
  a2 += __shfl_xor(a2, 16); a2 += __shfl_xor(a2, 32);
  a3 += __shfl_xor(a3, 16); a3 += __shfl_xor(a3, 32);
  a4 += __shfl_xor(a4, 16); a4 += __shfl_xor(a4, 32);
  a5 += __shfl_xor(a5, 16); a5 += __shfl_xor(a5, 32);
  a6 += __shfl_xor(a6, 16); a6 += __shfl_xor(a6, 32);
  a7 += __shfl_xor(a7, 16); a7 += __shfl_xor(a7, 32);

  if (qr == 0) {
    float inv = 1.f / fmaxf((float)dg, 1.f);
    uint4 o;
    o.x = (uint32_t)f2bf(a0 * inv) | ((uint32_t)f2bf(a1 * inv) << 16);
    o.y = (uint32_t)f2bf(a2 * inv) | ((uint32_t)f2bf(a3 * inv) << 16);
    o.z = (uint32_t)f2bf(a4 * inv) | ((uint32_t)f2bf(a5 * inv) << 16);
    o.w = (uint32_t)f2bf(a6 * inv) | ((uint32_t)f2bf(a7 * inv) << 16);
    *(uint4*)(hout + (size_t)d * DIM + c * 8) = o;
  }
}

// ---------------------------------------------------------------------------
// sage: out = act(hself@Wself + hneigh@Wneigh + bself + bneigh)
// Both W planes in LDS (64 KB). Burst A-loads + next-strip register prefetch.
// ---------------------------------------------------------------------------
template <bool ACT, bool OUT_BF16>
__global__ __launch_bounds__(256) void sage_kernel(
    const uint16_t* __restrict__ hself, const uint16_t* __restrict__ hneigh,
    const uint16_t* __restrict__ WfS, const uint16_t* __restrict__ WfN,
    const float* __restrict__ bS, const float* __restrict__ bN,
    void* __restrict__ outp, int n_dst) {
  __shared__ uint16_t wS[16384];
  __shared__ uint16_t wN[16384];
  {
    const uint4* gS = (const uint4*)WfS;
    const uint4* gN = (const uint4*)WfN;
    uint4* sS = (uint4*)wS;
    uint4* sN = (uint4*)wN;
    for (int i = threadIdx.x; i < 2048; i += 256) { sS[i] = gS[i]; sN[i] = gN[i]; }
  }
  __syncthreads();

  int wave = (blockIdx.x * 256 + threadIdx.x) >> 6;
  int nwaves = (gridDim.x * 256) >> 6;
  int lane = threadIdx.x & 63;
  int q = lane >> 4, m16 = lane & 15;

  float bv[8];
#pragma unroll
  for (int nt = 0; nt < 8; nt++)
    bv[nt] = bS[nt * 16 + m16] + bN[nt * 16 + m16];

  const int nstrips = n_dst / 16;
  int s = wave;
  bf16x8 XS[4], XN[4];
  if (s < nstrips) {
    size_t ro = (size_t)(s * 16 + m16) * DIM + q * 8;
#pragma unroll
    for (int kc = 0; kc < 4; kc++) {
      XS[kc] = *(const bf16x8*)(hself + ro + kc * 32);
      XN[kc] = *(const bf16x8*)(hneigh + ro + kc * 32);
    }
  }

  while (s < nstrips) {
    int sn = s + nwaves;
    bf16x8 YS[4], YN[4];
    if (sn < nstrips) {
      size_t ro = (size_t)(sn * 16 + m16) * DIM + q * 8;
#pragma unroll
      for (int kc = 0; kc < 4; kc++) {
        YS[kc] = *(const bf16x8*)(hself + ro + kc * 32);
        YN[kc] = *(const bf16x8*)(hneigh + ro + kc * 32);
      }
    }

    f32x4 acc[8];
#pragma unroll
    for (int nt = 0; nt < 8; nt++) acc[nt] = (f32x4){0.f, 0.f, 0.f, 0.f};

#pragma unroll
    for (int kc = 0; kc < 4; kc++) {
#pragma unroll
      for (int nt = 0; nt < 8; nt++) {
        size_t fo = (size_t)((kc * 8 + nt) * 64 + lane) * 8;
        bf16x8 ws = *(const bf16x8*)&wS[fo];
        bf16x8 wn = *(const bf16x8*)&wN[fo];
        acc[nt] = __builtin_amdgcn_mfma_f32_16x16x32_bf16(XS[kc], ws, acc[nt], 0, 0, 0);
        acc[nt] = __builtin_amdgcn_mfma_f32_16x16x32_bf16(XN[kc], wn, acc[nt], 0, 0, 0);
      }
    }

    int m0 = s * 16;
#pragma unroll
    for (int nt = 0; nt < 8; nt++)
#pragma unroll
      for (int r = 0; r < 4; r++) {
        float v = acc[nt][r] + bv[nt];
        if (ACT) v = fmaxf(v, 0.f);
        size_t o = (size_t)(m0 + q * 4 + r) * DIM + nt * 16 + m16;
        if (OUT_BF16) ((uint16_t*)outp)[o] = f2bf(v);
        else          ((float*)outp)[o] = v;
      }

#pragma unroll
    for (int i = 0; i < 4; i++) { XS[i] = YS[i]; XN[i] = YN[i]; }
    s = sn;
  }
}

// ---------------------------------------------------------------------------
// Workspace layout (bytes), total 92,498,304 (ws_size ~409.6 MB):
//   h      @ 0           200000*128 bf16 = 51,200,000
//   h1     @ 51,200,000   50000*128 bf16 = 12,800,000
//   hn     @ 64,000,000   50000*128 bf16 = 12,800,000
//   cnt0   @ 76,800,000   50000 int      =    200,000
//   cnt1   @ 77,000,000   10000 int      =     40,000
//   eslot0 @ 77,040,000   50000*64 int   = 12,800,000
//   eslot1 @ 89,840,000   10000*64 int   =  2,560,000
//   Wf     @ 92,400,000   3*16384 bf16   =     98,304
// ---------------------------------------------------------------------------
extern "C" void kernel_launch(void* const* d_in, const int* in_sizes, int n_in,
                              void* d_out, int out_size, void* d_ws, size_t ws_size,
                              hipStream_t stream) {
  const float* feat   = (const float*)d_in[0];
  const int* src0     = (const int*)d_in[1];
  const int* dst0     = (const int*)d_in[2];
  const int* src1     = (const int*)d_in[3];
  const int* dst1     = (const int*)d_in[4];
  const float* W_init = (const float*)d_in[5];
  const float* b_init = (const float*)d_in[6];
  const float* W_self = (const float*)d_in[7];
  const float* b_self = (const float*)d_in[8];
  const float* W_neigh= (const float*)d_in[9];
  const float* b_neigh= (const float*)d_in[10];

  char* ws = (char*)d_ws;
  uint16_t* h     = (uint16_t*)(ws + 0);
  uint16_t* h1    = (uint16_t*)(ws + 51200000);
  uint16_t* hn    = (uint16_t*)(ws + 64000000);
  int*      cnt0  = (int*)(ws + 76800000);
  int*      cnt1  = (int*)(ws + 77000000);
  int*      eslot0= (int*)(ws + 77040000);
  int*      eslot1= (int*)(ws + 89840000);
  uint16_t* WfI   = (uint16_t*)(ws + 92400000);
  uint16_t* WfS   = WfI + 16384;
  uint16_t* WfN   = WfS + 16384;

  // prep W fragments + zero cnt0/cnt1 (contiguous 60000 ints)
  prep_w_kernel<<<214, 512, 0, stream>>>(W_init, W_self, W_neigh, WfI, cnt0, 60000);

  // fused: edge scatter (even blocks) || h = relu(feat @ W_init + b) (odd)
  place_fc_kernel<<<PLACE_BLOCKS + FC_BLOCKS, 256, 0, stream>>>(
      src0, dst0, src1, dst1, cnt0, cnt1, eslot0, eslot1,
      feat, WfI, b_init, h);

  // ---- layer 0 ----
  agg_kernel<<<N_DST0 / 4, 256, 0, stream>>>(eslot0, cnt0, h, hn, N_DST0);
  sage_kernel<true, true><<<512, 256, 0, stream>>>(h, hn, WfS, WfN, b_self, b_neigh,
                                                   h1, N_DST0);

  // ---- layer 1 ----
  agg_kernel<<<N_DST1 / 4, 256, 0, stream>>>(eslot1, cnt1, h1, hn, N_DST1);
  sage_kernel<false, false><<<160, 256, 0, stream>>>(h1, hn, WfS, WfN, b_self, b_neigh,
                                                     d_out, N_DST1);
}